// Round 1
// baseline (1811.792 us; speedup 1.0000x reference)
//
#include <hip/hip_runtime.h>

// LSTM (B=2048, T=1024, I=8, H=64) + sigmoid(FC) head, fp32 VALU baseline.
//
// Layout: thread j (of 256) owns gate row j -> W_hh row in 64 VGPRs (static
// across the whole T loop), h streamed from LDS via wave-uniform broadcast
// float4 reads. BT=4 batch elems/block -> 512 blocks = 2 blocks/CU.
// Input projection fused (reads x: 64 MB total, instead of 2 GB of xg).

namespace {
constexpr int T_LEN = 1024;
constexpr int I_DIM = 8;
constexpr int H_DIM = 64;
constexpr int G_DIM = 256;  // 4*H
constexpr int BT    = 4;    // batch elements per block
constexpr int TS    = 16;   // timesteps of x staged per chunk

__device__ __forceinline__ float fsig(float x) {
  // 1/(1+e^-x); rcp/exp saturate correctly for |x| large.
  return __builtin_amdgcn_rcpf(1.f + __expf(-x));
}
__device__ __forceinline__ float ftanh(float x) {
  // tanh(x) = 1 - 2/(e^{2x}+1)
  return 1.f - 2.f * __builtin_amdgcn_rcpf(__expf(2.f * x) + 1.f);
}

__global__ __launch_bounds__(256, 2) void lstm_fused(
    const float* __restrict__ x,     // [B, T, 8]
    const float* __restrict__ W_ih,  // [256, 8]
    const float* __restrict__ W_hh,  // [256, 64]
    const float* __restrict__ b_ih,  // [256]
    const float* __restrict__ b_hh,  // [256]
    const float* __restrict__ fc_w,  // [64]
    const float* __restrict__ fc_b,  // [1]
    float* __restrict__ out) {       // [B]
  __shared__ __align__(16) float h_buf[BT][H_DIM];
  __shared__ __align__(16) float g_buf[BT][G_DIM];
  __shared__ __align__(16) float x_buf[TS][BT][I_DIM];

  const int tid = threadIdx.x;           // gate row j in [0,256)
  const int bBase = blockIdx.x * BT;

  // --- per-thread static weights (live whole kernel) ---
  float w[H_DIM];
#pragma unroll
  for (int k = 0; k < H_DIM; k += 4) {
    const float4 v = *reinterpret_cast<const float4*>(&W_hh[tid * H_DIM + k]);
    w[k] = v.x; w[k + 1] = v.y; w[k + 2] = v.z; w[k + 3] = v.w;
  }
  float wih[I_DIM];
#pragma unroll
  for (int i = 0; i < I_DIM; i += 4) {
    const float4 v = *reinterpret_cast<const float4*>(&W_ih[tid * I_DIM + i]);
    wih[i] = v.x; wih[i + 1] = v.y; wih[i + 2] = v.z; wih[i + 3] = v.w;
  }
  const float bsum = b_ih[tid] + b_hh[tid];

  // update-phase ownership: thread tid <-> (bt = tid>>6, jh = tid&63)
  const int my_bt = tid >> 6;
  const int my_jh = tid & 63;
  float creg = 0.f;                       // cell state, one per thread
  h_buf[my_bt][my_jh] = 0.f;              // h0 = 0 (256 == BT*H_DIM)
  __syncthreads();

  for (int t0 = 0; t0 < T_LEN; t0 += TS) {
    // stage TS timesteps of x for BT batch elems: 4*16*8 = 512 floats
#pragma unroll
    for (int r = 0; r < (BT * TS * I_DIM) / 256; ++r) {  // 2 iters
      const int idx = tid + r * 256;
      const int bt = idx >> 7;      // 128 contiguous floats per batch elem
      const int rem = idx & 127;    // tt*8 + i
      x_buf[rem >> 3][bt][rem & 7] =
          x[(size_t)(bBase + bt) * (T_LEN * I_DIM) + (size_t)t0 * I_DIM + rem];
    }
    __syncthreads();

    for (int tt = 0; tt < TS; ++tt) {
      // ---- phase 1: gate pre-activations, thread j does row j for all bt ----
      float acc[BT];
#pragma unroll
      for (int bt = 0; bt < BT; ++bt) {
        const float4 xa = *reinterpret_cast<const float4*>(&x_buf[tt][bt][0]);
        const float4 xb = *reinterpret_cast<const float4*>(&x_buf[tt][bt][4]);
        float a = bsum;
        a += wih[0] * xa.x + wih[1] * xa.y + wih[2] * xa.z + wih[3] * xa.w;
        a += wih[4] * xb.x + wih[5] * xb.y + wih[6] * xb.z + wih[7] * xb.w;
        acc[bt] = a;
      }
      // recurrent dot: interleave bt chains for ILP (only 2 waves/SIMD)
#pragma unroll
      for (int kk = 0; kk < H_DIM / 4; ++kk) {
#pragma unroll
        for (int bt = 0; bt < BT; ++bt) {
          const float4 hv =
              *reinterpret_cast<const float4*>(&h_buf[bt][4 * kk]);
          acc[bt] += w[4 * kk]     * hv.x;
          acc[bt] += w[4 * kk + 1] * hv.y;
          acc[bt] += w[4 * kk + 2] * hv.z;
          acc[bt] += w[4 * kk + 3] * hv.w;
        }
      }
#pragma unroll
      for (int bt = 0; bt < BT; ++bt) g_buf[bt][tid] = acc[bt];
      __syncthreads();

      // ---- phase 2: gate nonlinearities + c/h update (1 elem per thread) ----
      {
        const float gi = g_buf[my_bt][my_jh];          // torch order: i,f,g,o
        const float gf = g_buf[my_bt][64 + my_jh];
        const float gg = g_buf[my_bt][128 + my_jh];
        const float go = g_buf[my_bt][192 + my_jh];
        const float iv = fsig(gi);
        const float fv = fsig(gf);
        const float gv = ftanh(gg);
        const float ov = fsig(go);
        const float c = fv * creg + iv * gv;
        creg = c;
        h_buf[my_bt][my_jh] = ov * ftanh(c);
      }
      __syncthreads();
    }
  }

  // ---- epilogue: out[b] = sigmoid(hT . fc_w + fc_b) ----
  if (tid < BT) {
    float a = fc_b[0];
#pragma unroll
    for (int k = 0; k < H_DIM; ++k) a += h_buf[tid][k] * fc_w[k];
    out[bBase + tid] = fsig(a);
  }
}
}  // namespace

extern "C" void kernel_launch(void* const* d_in, const int* in_sizes, int n_in,
                              void* d_out, int out_size, void* d_ws,
                              size_t ws_size, hipStream_t stream) {
  const float* x    = (const float*)d_in[0];
  const float* W_ih = (const float*)d_in[1];
  const float* W_hh = (const float*)d_in[2];
  const float* b_ih = (const float*)d_in[3];
  const float* b_hh = (const float*)d_in[4];
  const float* fc_w = (const float*)d_in[5];
  const float* fc_b = (const float*)d_in[6];
  float* out = (float*)d_out;

  const int B = in_sizes[0] / (T_LEN * I_DIM);  // 2048
  lstm_fused<<<dim3(B / BT), dim3(256), 0, stream>>>(x, W_ih, W_hh, b_ih, b_hh,
                                                     fc_w, fc_b, out);
}

// Round 2
// 698.544 us; speedup vs baseline: 2.5937x; 2.5937x over previous
//
#include <hip/hip_runtime.h>

// LSTM (B=2048, T=1024, I=8, H=64) + sigmoid(FC), bf16-MFMA recurrent GEMM.
//
// Orientation: gates-as-M. Per block: 4 batch rows (N=16 tile, 4 used),
// 16 M-tiles of 16 gates, K=96 packed as [x(8) | 1-bias-channel | 0-pad | h(64)]
// -> 3 mfma_f32_16x16x32_bf16 per tile. Weights live as static A-fragments in
// VGPRs (4 tiles x 3 frags per wave). 512 blocks x 4 waves = 2 blocks/CU so
// barrier phases of independent blocks overlap on each SIMD; activations are
// 1 element/thread (fully lane-packed transcendentals).

namespace {
constexpr int T_LEN = 1024;
constexpr int BT = 4;            // batch rows per block
constexpr int TS = 32;           // timesteps of x staged per chunk
constexpr int HSTR = 72;         // h_lds row stride (bf16), 64 + 8 pad
constexpr int GSTR = 260;        // g_lds row stride (f32), 256 + 4 pad
constexpr int XSTR = TS * 8 + 8; // 264 (bf16), padded

typedef __attribute__((ext_vector_type(8))) short short8v;
typedef __attribute__((ext_vector_type(4))) float float4v;

__device__ __forceinline__ float fsig(float x) {
  return __builtin_amdgcn_rcpf(1.f + __expf(-x));
}
__device__ __forceinline__ float ftanh(float x) {
  return 1.f - 2.f * __builtin_amdgcn_rcpf(__expf(2.f * x) + 1.f);
}
__device__ __forceinline__ unsigned short f2bf(float f) {  // RNE
  unsigned int u = __float_as_uint(f);
  unsigned int r = ((u >> 16) & 1u) + 0x7fffu;
  return (unsigned short)((u + r) >> 16);
}

__global__ __launch_bounds__(256, 2) void lstm_mfma(
    const float* __restrict__ x,     // [B, T, 8]
    const float* __restrict__ W_ih,  // [256, 8]
    const float* __restrict__ W_hh,  // [256, 64]
    const float* __restrict__ b_ih,  // [256]
    const float* __restrict__ b_hh,  // [256]
    const float* __restrict__ fc_w,  // [64]
    const float* __restrict__ fc_b,  // [1]
    float* __restrict__ out) {       // [B]
  __shared__ __align__(16) unsigned short h_lds[16 * HSTR];  // rows 4..15 stay 0
  __shared__ __align__(16) float g_lds[BT * GSTR];
  __shared__ __align__(16) unsigned short x_lds[BT * XSTR];

  const int t = threadIdx.x;
  const int lane = t & 63;
  const int w = t >> 6;      // wave 0..3
  const int g4 = lane >> 4;  // quad 0..3
  const int nib = lane & 15; // MFMA m/n lane coord
  const int bBase = blockIdx.x * BT;

  // ---- static A fragments (weights), tiles q = 4w..4w+3 ----
  // A[m = 16q+nib][k = 8*g4 + j]; K layout: frag0 k=0..31 = [W_ih(8)|bias|0],
  // frag1 k=32..63 = W_hh[:,0:32], frag2 k=64..95 = W_hh[:,32:64].
  short8v a0[4], a1[4], a2[4];
  for (int qi = 0; qi < 4; ++qi) {
    const int n = 16 * (4 * w + qi) + nib;  // gate row 0..255
    short8v f0, f1, f2;
    for (int j = 0; j < 8; ++j) {
      const int k = 8 * g4 + j;  // 0..31 within frag
      float v0 = 0.f;
      if (k < 8) v0 = W_ih[n * 8 + k];
      else if (k == 8) v0 = b_ih[n] + b_hh[n];
      f0[j] = (short)f2bf(v0);
      f1[j] = (short)f2bf(W_hh[n * 64 + k]);
      f2[j] = (short)f2bf(W_hh[n * 64 + 32 + k]);
    }
    a0[qi] = f0; a1[qi] = f1; a2[qi] = f2;
  }

  // B frag0 static part: bias channel -> B[k=8][n] = 1.0 (lanes g4==1, j==0)
  short8v base_x = {0, 0, 0, 0, 0, 0, 0, 0};
  if (g4 == 1) base_x[0] = (short)0x3f80;  // bf16(1.0)
  const bool selx = (g4 == 0);

  // activation ownership: thread t <-> (b = t>>6, jh = t&63)
  const int b_act = t >> 6;
  const int jh = t & 63;
  float c = 0.f;

  for (int i = t; i < 16 * HSTR; i += 256) h_lds[i] = 0;  // h0 = 0 (+ghost rows)

  const float* xrow = x + (size_t)(bBase + (t >> 6)) * T_LEN * 8;
  const int off = t & 63;

  for (int chunk = 0; chunk < T_LEN / TS; ++chunk) {
    // ---- stage TS timesteps of x as bf16 (coalesced, once per 32 steps) ----
    {
      const float* s = xrow + chunk * (TS * 8);
#pragma unroll
      for (int r = 0; r < (TS * 8) / 64; ++r) {  // 4 rounds
        const int i = off + 64 * r;              // 0..255 within row-chunk
        x_lds[(t >> 6) * XSTR + i] = f2bf(s[i]);
      }
    }
    __syncthreads();  // also covers h_lds init on first pass

    for (int tt = 0; tt < TS; ++tt) {
      // ---- B fragments ----
      const short8v xv =
          *(const short8v*)&x_lds[(lane & 3) * XSTR + tt * 8];  // x[b][tt][0:8]
      const short8v fx = selx ? xv : base_x;
      const short8v fh0 = *(const short8v*)&h_lds[nib * HSTR + 8 * g4];
      const short8v fh1 = *(const short8v*)&h_lds[nib * HSTR + 32 + 8 * g4];

      // ---- 12 MFMAs: 4 tiles x (x + h0 + h1) ----
      float4v acc[4];
#pragma unroll
      for (int qi = 0; qi < 4; ++qi) {
        float4v a = {0.f, 0.f, 0.f, 0.f};
        a = __builtin_amdgcn_mfma_f32_16x16x32_bf16(a0[qi], fx, a, 0, 0, 0);
        a = __builtin_amdgcn_mfma_f32_16x16x32_bf16(a1[qi], fh0, a, 0, 0, 0);
        a = __builtin_amdgcn_mfma_f32_16x16x32_bf16(a2[qi], fh1, a, 0, 0, 0);
        acc[qi] = a;
      }
      // C layout: row(gate-in-tile) = 4*g4 + reg, col(batch) = nib
      if (nib < BT) {
#pragma unroll
        for (int qi = 0; qi < 4; ++qi) {
          *(float4v*)&g_lds[nib * GSTR + 16 * (4 * w + qi) + 4 * g4] = acc[qi];
        }
      }
      __syncthreads();

      // ---- activation: one (b, jh) element per thread ----
      const float gi = g_lds[b_act * GSTR + jh];
      const float gf = g_lds[b_act * GSTR + 64 + jh];
      const float gg = g_lds[b_act * GSTR + 128 + jh];
      const float go = g_lds[b_act * GSTR + 192 + jh];
      const float iv = fsig(gi);
      const float fv = fsig(gf);
      const float gv = ftanh(gg);
      const float ov = fsig(go);
      c = fv * c + iv * gv;
      const float h = ov * ftanh(c);
      h_lds[b_act * HSTR + jh] = f2bf(h);
      g_lds[b_act * GSTR + jh] = h;  // fp32 copy; only the final step's survives
      __syncthreads();
    }
  }

  // ---- epilogue: out[b] = sigmoid(hT . fc_w + fc_b) ----
  if (t < BT) {
    float a = fc_b[0];
    for (int k = 0; k < 64; ++k) a += g_lds[t * GSTR + k] * fc_w[k];
    out[bBase + t] = fsig(a);
  }
}
}  // namespace

extern "C" void kernel_launch(void* const* d_in, const int* in_sizes, int n_in,
                              void* d_out, int out_size, void* d_ws,
                              size_t ws_size, hipStream_t stream) {
  const float* x    = (const float*)d_in[0];
  const float* W_ih = (const float*)d_in[1];
  const float* W_hh = (const float*)d_in[2];
  const float* b_ih = (const float*)d_in[3];
  const float* b_hh = (const float*)d_in[4];
  const float* fc_w = (const float*)d_in[5];
  const float* fc_b = (const float*)d_in[6];
  float* out = (float*)d_out;

  const int B = in_sizes[0] / (T_LEN * 8);  // 2048
  lstm_mfma<<<dim3(B / BT), dim3(256), 0, stream>>>(x, W_ih, W_hh, b_ih, b_hh,
                                                    fc_w, fc_b, out);
}